// Round 3
// baseline (131.423 us; speedup 1.0000x reference)
//
#include <hip/hip_runtime.h>

#define NUM_FRAMES 1000
#define NUM_CAM    8
#define FROW       12              // frame row: {er,eg,eb,o0,o1,o2,o3,o4,o5,pad,pad,pad}
#define CROW       12              // cam channel row: {cx,cy,a2,a3, a4,k1,k2,k3, k4,pad,pad,pad}

__device__ __forceinline__ float softplus_acc(float x) {
    return (x > 20.0f) ? x : log1pf(expf(x));
}

// ---------------- setup: build frame table once into d_ws ----------------
__global__ void build_frame_table(const float* __restrict__ expo,
                                  const float* __restrict__ cp,
                                  float* __restrict__ ftab)
{
    int f = blockIdx.x * blockDim.x + threadIdx.x;
    if (f < NUM_FRAMES) {
        float e = expo[f];
        const float* c = cp + f * 8;
        float* d = ftab + f * FROW;
        d[0] = expf(e + c[0]);
        d[1] = expf(e);
        d[2] = expf(e + c[1]);
        d[3] = c[2]; d[4] = c[3]; d[5] = c[4];
        d[6] = c[5]; d[7] = c[6]; d[8] = c[7];
        d[9] = 0.f; d[10] = 0.f; d[11] = 0.f;
    }
}

// ---------------- per-pixel math ----------------
__device__ __forceinline__ void ppisp_px(
    float r, float g, float b, float px, float py,
    int cam, int frm, float invw, float invh,
    const float* __restrict__ ftab, const float* __restrict__ s_cam,
    float* o)
{
    const float4* fr = (const float4*)(ftab + frm * FROW);
    float4 f0 = fr[0];
    float4 f1 = fr[1];
    float  o5 = ((const float*)fr)[8];
    float er = f0.x, eg = f0.y, eb = f0.z;
    float o0 = f0.w, o1 = f1.x, o2 = f1.y, o3 = f1.z, o4 = f1.w;

    float nx = px * invw - 0.5f;
    float ny = py * invh - 0.5f;

    float xin[3] = { r * er, g * eg, b * eb };
    float xv[3];
    float k1v[3], k2v[3], k3v[3], k4v[3];
#pragma unroll
    for (int ch = 0; ch < 3; ++ch) {
        const float* c = s_cam + (cam * 3 + ch) * CROW;
        float4 c0 = *(const float4*)(c);      // cx,cy,a2,a3
        float4 c1 = *(const float4*)(c + 4);  // a4,k1,k2,k3
        float  k4 = c[8];
        float dx = nx - c0.x;
        float dy = ny - c0.y;
        float r2 = __builtin_fmaf(dx, dx, dy * dy);
        // Horner: 1 + a2 r2 + a3 r4 + a4 r6
        float vg = __builtin_fmaf(__builtin_fmaf(__builtin_fmaf(c1.x, r2, c0.w), r2, c0.z), r2, 1.0f);
        xv[ch] = xin[ch] * vg;
        k1v[ch] = c1.y; k2v[ch] = c1.z; k3v[ch] = c1.w; k4v[ch] = k4;
    }

    float m[3];
    m[0] = __builtin_fmaf(o0, xv[1], __builtin_fmaf(o1, xv[2], xv[0]));
    m[1] = __builtin_fmaf(o2, xv[0], __builtin_fmaf(o3, xv[2], xv[1]));
    m[2] = __builtin_fmaf(o4, xv[0], __builtin_fmaf(o5, xv[1], xv[2]));

#pragma unroll
    for (int ch = 0; ch < 3; ++ch) {
        float xg  = exp2f(k3v[ch] * log2f(fmaxf(m[ch], 1e-6f)));
        float den = __builtin_fmaf(k1v[ch] - 1.0f, xg, k2v[ch]);
        o[ch] = __builtin_fmaf(k1v[ch] * xg, __builtin_amdgcn_rcpf(den), k4v[ch]);
    }
}

__global__ __launch_bounds__(256, 6)
void ppisp_main(const float* __restrict__ rgb,
                const float* __restrict__ pc,
                const int*   __restrict__ cam_idx,
                const int*   __restrict__ frm_idx,
                const float* __restrict__ vigp,
                const float* __restrict__ crf,
                const float* __restrict__ ftab,
                const int*   __restrict__ resw_p,
                const int*   __restrict__ resh_p,
                float* __restrict__ out,
                int n)
{
    __shared__ __align__(16) float s_cam[NUM_CAM * 3 * CROW];

    for (int rr = threadIdx.x; rr < NUM_CAM * 3; rr += blockDim.x) {
        const float* v = vigp + rr * 5;
        const float* k = crf + rr * 4;
        float* d = s_cam + rr * CROW;
        d[0] = v[0]; d[1] = v[1]; d[2] = v[2]; d[3] = v[3];
        d[4] = v[4];
        d[5] = 0.3f + softplus_acc(k[0]);
        d[6] = 0.3f + softplus_acc(k[1]);
        d[7] = 0.1f + softplus_acc(k[2]);
        d[8] = k[3];
        d[9] = 0.f; d[10] = 0.f; d[11] = 0.f;
    }
    __syncthreads();

    float invw = 1.0f / (float)(*resw_p);
    float invh = 1.0f / (float)(*resh_p);

    const float4* rgb4 = (const float4*)rgb;
    const float4* pc4  = (const float4*)pc;
    const int4*   cam4 = (const int4*)cam_idx;
    const int4*   frm4 = (const int4*)frm_idx;
    float4* out4 = (float4*)out;

    int ngroups = n >> 2;
    int stride = gridDim.x * blockDim.x;
    for (int gi = blockIdx.x * blockDim.x + threadIdx.x; gi < ngroups; gi += stride) {
        float4 r0 = rgb4[gi * 3 + 0];
        float4 r1 = rgb4[gi * 3 + 1];
        float4 r2 = rgb4[gi * 3 + 2];
        float4 p0 = pc4[gi * 2 + 0];
        float4 p1 = pc4[gi * 2 + 1];
        int4 cm = cam4[gi];
        int4 fm = frm4[gi];

        float a[3], bb[3], c[3], d[3];
        ppisp_px(r0.x, r0.y, r0.z, p0.x, p0.y, cm.x, fm.x, invw, invh, ftab, s_cam, a);
        ppisp_px(r0.w, r1.x, r1.y, p0.z, p0.w, cm.y, fm.y, invw, invh, ftab, s_cam, bb);
        ppisp_px(r1.z, r1.w, r2.x, p1.x, p1.y, cm.z, fm.z, invw, invh, ftab, s_cam, c);
        ppisp_px(r2.y, r2.z, r2.w, p1.z, p1.w, cm.w, fm.w, invw, invh, ftab, s_cam, d);

        out4[gi * 3 + 0] = make_float4(a[0], a[1], a[2], bb[0]);
        out4[gi * 3 + 1] = make_float4(bb[1], bb[2], c[0], c[1]);
        out4[gi * 3 + 2] = make_float4(c[2], d[0], d[1], d[2]);
    }

    int rem_start = ngroups << 2;
    int nrem = n - rem_start;
    if (blockIdx.x == 0 && (int)threadIdx.x < nrem) {
        int i = rem_start + threadIdx.x;
        float o[3];
        ppisp_px(rgb[i * 3], rgb[i * 3 + 1], rgb[i * 3 + 2],
                 pc[i * 2], pc[i * 2 + 1],
                 cam_idx[i], frm_idx[i], invw, invh, ftab, s_cam, o);
        out[i * 3 + 0] = o[0];
        out[i * 3 + 1] = o[1];
        out[i * 3 + 2] = o[2];
    }
}

// ---------------- fallback (all-LDS, known-good 91.7us path) ----------------
__device__ __forceinline__ void ppisp_px_lds(
    float r, float g, float b, float px, float py,
    int cam, int frm, float invw, float invh,
    const float* __restrict__ s_frame, const float* __restrict__ s_cam,
    float* o)
{
    const float* fr = s_frame + frm * 9;
    float er = fr[0], eg = fr[1], eb = fr[2];
    float o0 = fr[3], o1 = fr[4], o2 = fr[5];
    float o3 = fr[6], o4 = fr[7], o5 = fr[8];
    float nx = px * invw - 0.5f;
    float ny = py * invh - 0.5f;
    float xin[3] = { r * er, g * eg, b * eb };
    float xv[3];
#pragma unroll
    for (int ch = 0; ch < 3; ++ch) {
        const float* c = s_cam + (cam * 3 + ch) * 9;
        float dx = nx - c[0], dy = ny - c[1];
        float r2 = dx * dx + dy * dy;
        float vg = __builtin_fmaf(__builtin_fmaf(__builtin_fmaf(c[4], r2, c[3]), r2, c[2]), r2, 1.0f);
        xv[ch] = xin[ch] * vg;
    }
    float m[3];
    m[0] = xv[0] + o0 * xv[1] + o1 * xv[2];
    m[1] = o2 * xv[0] + xv[1] + o3 * xv[2];
    m[2] = o4 * xv[0] + o5 * xv[1] + xv[2];
#pragma unroll
    for (int ch = 0; ch < 3; ++ch) {
        const float* c = s_cam + (cam * 3 + ch) * 9;
        float k1 = c[5], k2 = c[6], k3 = c[7], k4 = c[8];
        float xg  = exp2f(k3 * log2f(fmaxf(m[ch], 1e-6f)));
        float den = __builtin_fmaf(k1 - 1.0f, xg, k2);
        o[ch] = k1 * xg * __builtin_amdgcn_rcpf(den) + k4;
    }
}

__global__ __launch_bounds__(256, 4)
void ppisp_fallback(const float* __restrict__ rgb, const float* __restrict__ pc,
                    const int* __restrict__ cam_idx, const int* __restrict__ frm_idx,
                    const float* __restrict__ expo, const float* __restrict__ vigp,
                    const float* __restrict__ cp, const float* __restrict__ crf,
                    const int* __restrict__ resw_p, const int* __restrict__ resh_p,
                    float* __restrict__ out, int n)
{
    __shared__ float s_frame[NUM_FRAMES * 9];
    __shared__ float s_cam[NUM_CAM * 3 * 9];
    for (int f = threadIdx.x; f < NUM_FRAMES; f += blockDim.x) {
        float e = expo[f];
        const float* c = cp + f * 8;
        float* d = s_frame + f * 9;
        d[0] = expf(e + c[0]); d[1] = expf(e); d[2] = expf(e + c[1]);
        d[3] = c[2]; d[4] = c[3]; d[5] = c[4];
        d[6] = c[5]; d[7] = c[6]; d[8] = c[7];
    }
    for (int rr = threadIdx.x; rr < NUM_CAM * 3; rr += blockDim.x) {
        const float* v = vigp + rr * 5;
        const float* k = crf + rr * 4;
        float* d = s_cam + rr * 9;
        d[0] = v[0]; d[1] = v[1]; d[2] = v[2]; d[3] = v[3]; d[4] = v[4];
        d[5] = 0.3f + softplus_acc(k[0]);
        d[6] = 0.3f + softplus_acc(k[1]);
        d[7] = 0.1f + softplus_acc(k[2]);
        d[8] = k[3];
    }
    __syncthreads();
    float invw = 1.0f / (float)(*resw_p);
    float invh = 1.0f / (float)(*resh_p);
    const float4* rgb4 = (const float4*)rgb;
    const float4* pc4  = (const float4*)pc;
    const int4* cam4 = (const int4*)cam_idx;
    const int4* frm4 = (const int4*)frm_idx;
    float4* out4 = (float4*)out;
    int ngroups = n >> 2;
    int stride = gridDim.x * blockDim.x;
    for (int gi = blockIdx.x * blockDim.x + threadIdx.x; gi < ngroups; gi += stride) {
        float4 r0 = rgb4[gi * 3 + 0], r1 = rgb4[gi * 3 + 1], r2 = rgb4[gi * 3 + 2];
        float4 p0 = pc4[gi * 2 + 0], p1 = pc4[gi * 2 + 1];
        int4 cm = cam4[gi]; int4 fm = frm4[gi];
        float a[3], bb[3], c[3], d[3];
        ppisp_px_lds(r0.x, r0.y, r0.z, p0.x, p0.y, cm.x, fm.x, invw, invh, s_frame, s_cam, a);
        ppisp_px_lds(r0.w, r1.x, r1.y, p0.z, p0.w, cm.y, fm.y, invw, invh, s_frame, s_cam, bb);
        ppisp_px_lds(r1.z, r1.w, r2.x, p1.x, p1.y, cm.z, fm.z, invw, invh, s_frame, s_cam, c);
        ppisp_px_lds(r2.y, r2.z, r2.w, p1.z, p1.w, cm.w, fm.w, invw, invh, s_frame, s_cam, d);
        out4[gi * 3 + 0] = make_float4(a[0], a[1], a[2], bb[0]);
        out4[gi * 3 + 1] = make_float4(bb[1], bb[2], c[0], c[1]);
        out4[gi * 3 + 2] = make_float4(c[2], d[0], d[1], d[2]);
    }
    int rem_start = ngroups << 2;
    int nrem = n - rem_start;
    if (blockIdx.x == 0 && (int)threadIdx.x < nrem) {
        int i = rem_start + threadIdx.x;
        float o[3];
        ppisp_px_lds(rgb[i * 3], rgb[i * 3 + 1], rgb[i * 3 + 2], pc[i * 2], pc[i * 2 + 1],
                     cam_idx[i], frm_idx[i], invw, invh, s_frame, s_cam, o);
        out[i * 3 + 0] = o[0]; out[i * 3 + 1] = o[1]; out[i * 3 + 2] = o[2];
    }
}

extern "C" void kernel_launch(void* const* d_in, const int* in_sizes, int n_in,
                              void* d_out, int out_size, void* d_ws, size_t ws_size,
                              hipStream_t stream)
{
    const float* rgb  = (const float*)d_in[0];
    const float* pc   = (const float*)d_in[1];
    const int*   cam  = (const int*)d_in[2];
    const int*   frm  = (const int*)d_in[3];
    const float* expo = (const float*)d_in[4];
    const float* vigp = (const float*)d_in[5];
    const float* cp   = (const float*)d_in[6];
    const float* crf  = (const float*)d_in[7];
    const int*   resw = (const int*)d_in[8];
    const int*   resh = (const int*)d_in[9];
    float* out = (float*)d_out;

    int n = in_sizes[2];
    int ngroups = (n + 3) / 4;
    int blocks = (ngroups + 255) / 256;
    if (blocks > 2048) blocks = 2048;

    size_t ftab_bytes = (size_t)NUM_FRAMES * FROW * sizeof(float);
    if (ws_size >= ftab_bytes) {
        float* ftab = (float*)d_ws;
        build_frame_table<<<dim3((NUM_FRAMES + 255) / 256), dim3(256), 0, stream>>>(expo, cp, ftab);
        ppisp_main<<<dim3(blocks), dim3(256), 0, stream>>>(
            rgb, pc, cam, frm, vigp, crf, ftab, resw, resh, out, n);
    } else {
        ppisp_fallback<<<dim3(blocks), dim3(256), 0, stream>>>(
            rgb, pc, cam, frm, expo, vigp, cp, crf, resw, resh, out, n);
    }
}

// Round 4
// 94.070 us; speedup vs baseline: 1.3971x; 1.3971x over previous
//
#include <hip/hip_runtime.h>

#define NUM_FRAMES 1000
#define NUM_CAM    8
#define CROW       12   // cam channel row: {cx,cy,a2,a3, a4,k1,k2,k3, k4,pad,pad,pad}

typedef _Float16 h8 __attribute__((ext_vector_type(8)));

__device__ __forceinline__ float softplus_acc(float x) {
    return (x > 20.0f) ? x : log1pf(expf(x));
}

// Per-pixel ISP math.
//  s_frame8[f] = f16x8 {er,eg,eb,o0,o1,o2,o3,o4}; s_o5h[f] = f16 o5
//  s_cam[(cam*3+ch)*CROW] = {cx,cy,a2,a3, a4,k1,k2,k3, k4,...}
__device__ __forceinline__ void ppisp_px(
    float r, float g, float b, float px, float py,
    int cam, int frm, float invw, float invh,
    const h8* __restrict__ s_frame8, const _Float16* __restrict__ s_o5h,
    const float* __restrict__ s_cam,
    float* o)
{
    h8 fr = s_frame8[frm];
    float er = (float)fr[0], eg = (float)fr[1], eb = (float)fr[2];
    float o0 = (float)fr[3], o1 = (float)fr[4], o2 = (float)fr[5];
    float o3 = (float)fr[6], o4 = (float)fr[7];
    float o5 = (float)s_o5h[frm];

    float nx = px * invw - 0.5f;
    float ny = py * invh - 0.5f;

    float xin[3] = { r * er, g * eg, b * eb };
    float xv[3];
    float k1v[3], k2v[3], k3v[3], k4v[3];
#pragma unroll
    for (int ch = 0; ch < 3; ++ch) {
        const float* c = s_cam + (cam * 3 + ch) * CROW;
        float4 c0 = *(const float4*)(c);      // cx,cy,a2,a3
        float4 c1 = *(const float4*)(c + 4);  // a4,k1,k2,k3
        float  k4 = c[8];
        float dx = nx - c0.x;
        float dy = ny - c0.y;
        float r2 = __builtin_fmaf(dx, dx, dy * dy);
        float vg = __builtin_fmaf(__builtin_fmaf(__builtin_fmaf(c1.x, r2, c0.w), r2, c0.z), r2, 1.0f);
        xv[ch] = xin[ch] * vg;
        k1v[ch] = c1.y; k2v[ch] = c1.z; k3v[ch] = c1.w; k4v[ch] = k4;
    }

    float m[3];
    m[0] = __builtin_fmaf(o0, xv[1], __builtin_fmaf(o1, xv[2], xv[0]));
    m[1] = __builtin_fmaf(o2, xv[0], __builtin_fmaf(o3, xv[2], xv[1]));
    m[2] = __builtin_fmaf(o4, xv[0], __builtin_fmaf(o5, xv[1], xv[2]));

#pragma unroll
    for (int ch = 0; ch < 3; ++ch) {
        float xg  = exp2f(k3v[ch] * log2f(fmaxf(m[ch], 1e-6f)));
        float den = __builtin_fmaf(k1v[ch] - 1.0f, xg, k2v[ch]);
        o[ch] = __builtin_fmaf(k1v[ch] * xg, __builtin_amdgcn_rcpf(den), k4v[ch]);
    }
}

__global__ __launch_bounds__(256, 8)
void ppisp_kernel(const float* __restrict__ rgb,
                  const float* __restrict__ pc,
                  const int*   __restrict__ cam_idx,
                  const int*   __restrict__ frm_idx,
                  const float* __restrict__ expo,
                  const float* __restrict__ vigp,
                  const float* __restrict__ cp,
                  const float* __restrict__ crf,
                  const int*   __restrict__ resw_p,
                  const int*   __restrict__ resh_p,
                  float* __restrict__ out,
                  int n)
{
    __shared__ __align__(16) h8 s_frame8[NUM_FRAMES];          // 16 KB
    __shared__ _Float16 s_o5h[NUM_FRAMES];                     // 2 KB
    __shared__ __align__(16) float s_cam[NUM_CAM * 3 * CROW];  // 1.125 KB

    // ---- build frame table (hoists all frame-dependent exps) ----
    for (int f = threadIdx.x; f < NUM_FRAMES; f += blockDim.x) {
        float e = expo[f];
        const float* c = cp + f * 8;
        h8 row;
        row[0] = (_Float16)expf(e + c[0]);
        row[1] = (_Float16)expf(e);
        row[2] = (_Float16)expf(e + c[1]);
        row[3] = (_Float16)c[2];
        row[4] = (_Float16)c[3];
        row[5] = (_Float16)c[4];
        row[6] = (_Float16)c[5];
        row[7] = (_Float16)c[6];
        s_frame8[f] = row;
        s_o5h[f] = (_Float16)c[7];
    }
    // ---- build camera table (hoists softplus) ----
    for (int rr = threadIdx.x; rr < NUM_CAM * 3; rr += blockDim.x) {
        const float* v = vigp + rr * 5;
        const float* k = crf + rr * 4;
        float* d = s_cam + rr * CROW;
        d[0] = v[0]; d[1] = v[1]; d[2] = v[2]; d[3] = v[3];
        d[4] = v[4];
        d[5] = 0.3f + softplus_acc(k[0]);
        d[6] = 0.3f + softplus_acc(k[1]);
        d[7] = 0.1f + softplus_acc(k[2]);
        d[8] = k[3];
        d[9] = 0.f; d[10] = 0.f; d[11] = 0.f;
    }
    __syncthreads();

    float invw = 1.0f / (float)(*resw_p);
    float invh = 1.0f / (float)(*resh_p);

    const float4* rgb4 = (const float4*)rgb;
    const float4* pc4  = (const float4*)pc;
    const int4*   cam4 = (const int4*)cam_idx;
    const int4*   frm4 = (const int4*)frm_idx;
    float4* out4 = (float4*)out;

    int ngroups = n >> 2;
    int stride = gridDim.x * blockDim.x;
    for (int gi = blockIdx.x * blockDim.x + threadIdx.x; gi < ngroups; gi += stride) {
        float4 r0 = rgb4[gi * 3 + 0];
        float4 r1 = rgb4[gi * 3 + 1];
        float4 r2 = rgb4[gi * 3 + 2];
        float4 p0 = pc4[gi * 2 + 0];
        float4 p1 = pc4[gi * 2 + 1];
        int4 cm = cam4[gi];
        int4 fm = frm4[gi];

        float a[3], bb[3], c[3], d[3];
        ppisp_px(r0.x, r0.y, r0.z, p0.x, p0.y, cm.x, fm.x, invw, invh, s_frame8, s_o5h, s_cam, a);
        ppisp_px(r0.w, r1.x, r1.y, p0.z, p0.w, cm.y, fm.y, invw, invh, s_frame8, s_o5h, s_cam, bb);
        ppisp_px(r1.z, r1.w, r2.x, p1.x, p1.y, cm.z, fm.z, invw, invh, s_frame8, s_o5h, s_cam, c);
        ppisp_px(r2.y, r2.z, r2.w, p1.z, p1.w, cm.w, fm.w, invw, invh, s_frame8, s_o5h, s_cam, d);

        out4[gi * 3 + 0] = make_float4(a[0], a[1], a[2], bb[0]);
        out4[gi * 3 + 1] = make_float4(bb[1], bb[2], c[0], c[1]);
        out4[gi * 3 + 2] = make_float4(c[2], d[0], d[1], d[2]);
    }

    // tail (n not divisible by 4)
    int rem_start = ngroups << 2;
    int nrem = n - rem_start;
    if (blockIdx.x == 0 && (int)threadIdx.x < nrem) {
        int i = rem_start + threadIdx.x;
        float o[3];
        ppisp_px(rgb[i * 3], rgb[i * 3 + 1], rgb[i * 3 + 2],
                 pc[i * 2], pc[i * 2 + 1],
                 cam_idx[i], frm_idx[i], invw, invh, s_frame8, s_o5h, s_cam, o);
        out[i * 3 + 0] = o[0];
        out[i * 3 + 1] = o[1];
        out[i * 3 + 2] = o[2];
    }
}

extern "C" void kernel_launch(void* const* d_in, const int* in_sizes, int n_in,
                              void* d_out, int out_size, void* d_ws, size_t ws_size,
                              hipStream_t stream)
{
    const float* rgb  = (const float*)d_in[0];
    const float* pc   = (const float*)d_in[1];
    const int*   cam  = (const int*)d_in[2];
    const int*   frm  = (const int*)d_in[3];
    const float* expo = (const float*)d_in[4];
    const float* vigp = (const float*)d_in[5];
    const float* cp   = (const float*)d_in[6];
    const float* crf  = (const float*)d_in[7];
    const int*   resw = (const int*)d_in[8];
    const int*   resh = (const int*)d_in[9];
    float* out = (float*)d_out;

    int n = in_sizes[2];   // number of pixels

    int ngroups = (n + 3) / 4;
    int blocks = (ngroups + 255) / 256;
    if (blocks > 2048) blocks = 2048;

    ppisp_kernel<<<dim3(blocks), dim3(256), 0, stream>>>(
        rgb, pc, cam, frm, expo, vigp, cp, crf, resw, resh, out, n);
}